// Round 5
// baseline (940.518 us; speedup 1.0000x reference)
//
#include <hip/hip_runtime.h>
#include <stdint.h>

#define NWIN 4096
#define NTOK 49
#define CDIM 192
#define NH   6
#define HD   32

typedef __attribute__((ext_vector_type(8))) short short8;
typedef __attribute__((ext_vector_type(4))) float floatx4;
typedef unsigned short ushort_t;
typedef unsigned int uint32;

// LDS row strides in bf16 elements: multiples of 8 (16-B alignment for b128),
// dword-stride mod 32 in {4,18} -> <=2-way bank aliasing (free per m136).
#define XS_S 200   // x rows [49][200]; dead after af preload -> attn output
#define QK_S 136   // per-pass q|k rows [49][136]: hh*64+{0..31}=q, +32..63=k
#define P_S  72    // probability rows [49][72] (cols 49..63 exact-0 K-pad)
#define VT_S 72    // V^T rows [64][72]: row = hh*32+d, col = token (>=49 -> 0)

// Manual layout (ushort offsets). Padded MFMA row-tiles (rows 49..63) do
// masked overrun READS that must stay inside the block's LDS:
//   xs overrun -> qks, qks overrun -> Pb, Pb overrun -> Vt; Vt never overruns.
#define OFF_XS   0              // 49*200 = 9800
#define OFF_QKS  9800           // 49*136 = 6664
#define OFF_PB   16464          // 49*72  = 3528
#define OFF_VT   19992          // 64*72  = 4608
#define LDS_TOT  24600          // 49200 B -> 3 blocks/CU (LDS limit)

__device__ __forceinline__ ushort_t f2bf(float f) {
    uint32 u = __float_as_uint(f);
    u += 0x7fffu + ((u >> 16) & 1u);   // round-to-nearest-even
    return (ushort_t)(u >> 16);
}

// Pre-convert weights to bf16 and pre-gather rpe bias into [6][49][64] fp32.
__global__ void wmsa_prologue(const float* __restrict__ qkv_w,
                              const float* __restrict__ proj_w,
                              const float* __restrict__ rpe_table,
                              const int*   __restrict__ rpe_idx,
                              ushort_t* __restrict__ qkv_wb,
                              ushort_t* __restrict__ proj_wb,
                              float* __restrict__ biasws)
{
    int i = blockIdx.x * 256 + threadIdx.x;
    if (i < 110592) {
        qkv_wb[i] = f2bf(qkv_w[i]);
    } else if (i < 147456) {
        proj_wb[i - 110592] = f2bf(proj_w[i - 110592]);
    } else if (i < 147456 + NH * NTOK * 64) {
        int r = i - 147456;
        int h = r / (NTOK * 64);
        int rem = r - h * (NTOK * 64);
        int n = rem >> 6, m = rem & 63;
        biasws[r] = (m < NTOK) ? rpe_table[rpe_idx[n * NTOK + m] * NH + h] : 0.f;
    }
}

// M-SPLIT GEMM: wave owns 16 query rows, computes ALL 12 col-tiles for them.
// Register plan: af 24 persistent + <=36 phase accum + arch misc -> unified
// well under the 170 cap from (256,3), so 3 waves/SIMD = 3 blocks/CU (= LDS cap).
// Rounds 3/4 both stuck at 2 waves/SIMD with ~188 unified (92 arch + 96 accum).
__global__ __launch_bounds__(256, 3)
void wmsa_mfma(const float* __restrict__ x,
               const ushort_t* __restrict__ qkv_wb,
               const float* __restrict__ qkv_b,
               const ushort_t* __restrict__ proj_wb,
               const float* __restrict__ proj_b,
               const float* __restrict__ biasws,
               float* __restrict__ out)
{
    __shared__ alignas(16) ushort_t lds[LDS_TOT];
    ushort_t* const xs  = lds + OFF_XS;    // x until af preload, then attn out
    ushort_t* const qks = lds + OFF_QKS;   // per-pass q|k (2 heads)
    ushort_t* const Pb  = lds + OFF_PB;    // probabilities, wave-local rows
    ushort_t* const Vt  = lds + OFF_VT;    // per-pass V^T (2 heads), zero-pad

    const int b    = blockIdx.x;
    const int t    = threadIdx.x;
    const int w    = t >> 6;      // wave 0..3
    const int lane = t & 63;
    const int quad = lane >> 4;   // MFMA k-group
    const int c    = lane & 15;   // MFMA row/col within group
    const float scale = 0.17677669529663687f;   // 32^-0.5
    const floatx4 zf = {0.f, 0.f, 0.f, 0.f};

    const float* xb = x + (size_t)b * (NTOK * CDIM);

    // ---------- stage x -> bf16 LDS (coalesced float4) ----------
    for (int i = t; i < (NTOK * CDIM) / 4; i += 256) {
        int e = i * 4;
        int n = e / CDIM, d = e - n * CDIM;
        float4 v = *(const float4*)(xb + e);
        ushort_t* p = &xs[n * XS_S + d];
        p[0] = f2bf(v.x); p[1] = f2bf(v.y); p[2] = f2bf(v.z); p[3] = f2bf(v.w);
    }
    __syncthreads();                                   // (A) x staged

    // ---------- persistent A-fragments: THIS wave's 16 rows only (24 VGPR) ---
    // A layout (16x16x32): m = lane&15 -> row w*16+c, k = quad*8+j.
    // w==3 rows 49..63 read garbage (qks region) -> all consumers masked.
    // xs is DEAD after this: x is consumed only via af for all 3 passes.
    const int arow = w * 16 + c;
    short8 af[6];
    #pragma unroll
    for (int ks = 0; ks < 6; ++ks)
        af[ks] = *(const short8*)&xs[arow * XS_S + ks * 32 + quad * 8];

    for (int pass = 0; pass < 3; ++pass) {
        // ----- qkv GEMM: 12 tiles (4 tile-groups x {q,k,v}), 3 chains each ----
        #pragma unroll
        for (int tg = 0; tg < 4; ++tg) {
            const int hh   = tg >> 1;
            const int half = tg & 1;
            const int jb   = (2 * pass + hh) * HD + half * 16 + c;
            const ushort_t* wp0 = qkv_wb + jb * CDIM + quad * 8;

            floatx4 acc[3];
            #pragma unroll
            for (int s = 0; s < 3; ++s) acc[s] = zf;

            #pragma unroll
            for (int ks = 0; ks < 6; ++ks) {
                #pragma unroll
                for (int s = 0; s < 3; ++s) {
                    short8 bf = *(const short8*)(wp0 + s * (CDIM * CDIM) + ks * 32);
                    acc[s] = __builtin_amdgcn_mfma_f32_16x16x32_bf16(
                        af[ks], bf, acc[s], 0, 0, 0);
                }
            }

            float bq = qkv_b[jb];
            float bk = qkv_b[CDIM + jb];
            float bv = qkv_b[2 * CDIM + jb];
            const int qcol = hh * 64 + half * 16 + c;     // q col; k at +32
            const int vrow = hh * HD + half * 16 + c;     // V^T row (d index)
            #pragma unroll
            for (int r = 0; r < 4; ++r) {
                int n = w * 16 + quad * 4 + r;   // C: col=lane&15, row=quad*4+reg
                if (n < NTOK) {
                    qks[n * QK_S + qcol]      = f2bf((acc[0][r] + bq) * scale);
                    qks[n * QK_S + qcol + 32] = f2bf(acc[1][r] + bk);
                }
                Vt[vrow * VT_S + n] = (n < NTOK) ? f2bf(acc[2][r] + bv)
                                                 : (ushort_t)0;
            }
        }
        __syncthreads();   // (B_p) qks + Vt ready

        // ----- attention, 2 heads, no intra-pass barriers (Pb wave-local) ----
        #pragma unroll
        for (int hh = 0; hh < 2; ++hh) {
            const int h = pass * 2 + hh;

            short8 aq = *(const short8*)&qks[arow * QK_S + hh * 64 + quad * 8];
            floatx4 sacc[4];
            #pragma unroll
            for (int nt = 0; nt < 4; ++nt) {
                short8 bk8 = *(const short8*)&qks[(nt * 16 + c) * QK_S + hh * 64 + 32 + quad * 8];
                sacc[nt] = __builtin_amdgcn_mfma_f32_16x16x32_bf16(aq, bk8, zf, 0, 0, 0);
            }

            const float* bpb = biasws + h * (NTOK * 64);
            #pragma unroll
            for (int r = 0; r < 4; ++r) {
                int n  = w * 16 + quad * 4 + r;
                int nc = (n < NTOK) ? n : (NTOK - 1);   // clamp for pad rows
                float sv[4];
                #pragma unroll
                for (int nt = 0; nt < 4; ++nt) {
                    int col = nt * 16 + c;
                    float bias = bpb[nc * 64 + col];
                    sv[nt] = (col < NTOK) ? (sacc[nt][r] + bias) : -1e30f;
                }
                float m0 = fmaxf(fmaxf(sv[0], sv[1]), fmaxf(sv[2], sv[3]));
                m0 = fmaxf(m0, __shfl_xor(m0, 1));
                m0 = fmaxf(m0, __shfl_xor(m0, 2));
                m0 = fmaxf(m0, __shfl_xor(m0, 4));
                m0 = fmaxf(m0, __shfl_xor(m0, 8));
                float ex[4], s0 = 0.f;
                #pragma unroll
                for (int nt = 0; nt < 4; ++nt) { ex[nt] = __expf(sv[nt] - m0); s0 += ex[nt]; }
                s0 += __shfl_xor(s0, 1);
                s0 += __shfl_xor(s0, 2);
                s0 += __shfl_xor(s0, 4);
                s0 += __shfl_xor(s0, 8);
                float inv = 1.f / s0;
                if (n < NTOK) {
                    #pragma unroll
                    for (int nt = 0; nt < 4; ++nt)   // cols 49..63 exact 0 (K-pad)
                        Pb[n * P_S + nt * 16 + c] = f2bf(ex[nt] * inv);
                }
            }

            // PV: [16x64(pad)] @ [64x32]; output straight to xs (x is dead).
            floatx4 o0 = zf, o1 = zf;
            #pragma unroll
            for (int ks2 = 0; ks2 < 2; ++ks2) {
                short8 ap  = *(const short8*)&Pb[arow * P_S + ks2 * 32 + quad * 8];
                short8 bv0 = *(const short8*)&Vt[(hh * HD + c) * VT_S + ks2 * 32 + quad * 8];
                short8 bv1 = *(const short8*)&Vt[(hh * HD + 16 + c) * VT_S + ks2 * 32 + quad * 8];
                o0 = __builtin_amdgcn_mfma_f32_16x16x32_bf16(ap, bv0, o0, 0, 0, 0);
                o1 = __builtin_amdgcn_mfma_f32_16x16x32_bf16(ap, bv1, o1, 0, 0, 0);
            }
            #pragma unroll
            for (int r = 0; r < 4; ++r) {
                int n = w * 16 + quad * 4 + r;
                if (n < NTOK) {
                    xs[n * XS_S + h * HD + c]      = f2bf(o0[r]);
                    xs[n * XS_S + h * HD + 16 + c] = f2bf(o1[r]);
                }
            }
        }
        if (pass < 2) __syncthreads();   // (C_p) release qks/Vt for next pass
    }

    // ---------- output projection: wave's 16 rows x all 12 col-tiles ----------
    // No barrier: proj A reads ONLY this wave's own xs rows, which this wave
    // wrote (in-wave ds ordering via lgkmcnt). Rows 49..63 garbage -> masked.
    short8 ap6[6];
    #pragma unroll
    for (int ks = 0; ks < 6; ++ks)
        ap6[ks] = *(const short8*)&xs[arow * XS_S + ks * 32 + quad * 8];

    #pragma unroll
    for (int tg = 0; tg < 4; ++tg) {
        floatx4 pacc[3];
        #pragma unroll
        for (int tt = 0; tt < 3; ++tt) pacc[tt] = zf;

        #pragma unroll
        for (int ks = 0; ks < 6; ++ks) {
            #pragma unroll
            for (int tt = 0; tt < 3; ++tt) {
                int j = (tg * 3 + tt) * 16 + c;
                short8 bf = *(const short8*)&proj_wb[j * CDIM + ks * 32 + quad * 8];
                pacc[tt] = __builtin_amdgcn_mfma_f32_16x16x32_bf16(
                    ap6[ks], bf, pacc[tt], 0, 0, 0);
            }
        }
        #pragma unroll
        for (int tt = 0; tt < 3; ++tt) {
            int j = (tg * 3 + tt) * 16 + c;
            float pb = proj_b[j];
            #pragma unroll
            for (int r = 0; r < 4; ++r) {
                int n = w * 16 + quad * 4 + r;
                if (n < NTOK)
                    out[((size_t)b * NTOK + n) * CDIM + j] = pacc[tt][r] + pb;
            }
        }
    }
}

extern "C" void kernel_launch(void* const* d_in, const int* in_sizes, int n_in,
                              void* d_out, int out_size, void* d_ws, size_t ws_size,
                              hipStream_t stream)
{
    const float* x      = (const float*)d_in[0];
    const float* qkv_w  = (const float*)d_in[1];
    const float* qkv_b  = (const float*)d_in[2];
    const float* proj_w = (const float*)d_in[3];
    const float* proj_b = (const float*)d_in[4];
    const float* rpe_t  = (const float*)d_in[5];
    const int*   rpe_i  = (const int*)d_in[6];
    float*       o      = (float*)d_out;

    // workspace layout: qkv_w bf16 (221184 B) | proj_w bf16 (73728 B) | bias fp32 (75264 B)
    ushort_t* qkv_wb  = (ushort_t*)d_ws;
    ushort_t* proj_wb = qkv_wb + 110592;
    float*    biasws  = (float*)((char*)d_ws + (110592 + 36864) * sizeof(ushort_t));

    int tot = 147456 + NH * NTOK * 64;
    wmsa_prologue<<<dim3((tot + 255) / 256), dim3(256), 0, stream>>>(
        qkv_w, proj_w, rpe_t, rpe_i, qkv_wb, proj_wb, biasws);
    wmsa_mfma<<<dim3(NWIN), dim3(256), 0, stream>>>(
        x, qkv_wb, qkv_b, proj_wb, proj_b, biasws, o);
}

// Round 6
// 504.867 us; speedup vs baseline: 1.8629x; 1.8629x over previous
//
#include <hip/hip_runtime.h>
#include <stdint.h>

#define NWIN 4096
#define NTOK 49
#define CDIM 192
#define NH   6
#define HD   32

typedef __attribute__((ext_vector_type(8))) short short8;
typedef __attribute__((ext_vector_type(4))) float floatx4;
typedef unsigned short ushort_t;
typedef unsigned int uint32;

// LDS row strides in bf16 elements: multiples of 8 (16-B alignment for b128),
// dword-stride mod 32 in {4,18} -> <=2-way bank aliasing (free per m136).
#define XS_S 200   // x rows [49][200]; overwritten by attn-out only after pass-2 GEMM
#define QK_S 136   // per-pass q|k rows [49][136]: hh*64+{0..31}=q, +32..63=k
#define P_S  72    // probability rows [49][72] (cols 49..63 exact-0 K-pad)
#define VT_S 72    // V^T rows [64][72]: row = hh*32+d, col = token (>=49 -> 0)

// Manual layout (ushort offsets). Padded MFMA row-tiles (rows 49..63) do
// masked overrun READS that must stay inside the block's LDS:
//   xs overrun -> qks, qks overrun -> Pb, Pb overrun -> Vt; Vt never overruns.
#define OFF_XS   0              // 49*200 = 9800
#define OFF_QKS  9800           // 49*136 = 6664
#define OFF_PB   16464          // 49*72  = 3528
#define OFF_VT   19992          // 64*72  = 4608
#define LDS_TOT  24600          // 49200 B -> 3 blocks/CU (LDS limit)

__device__ __forceinline__ ushort_t f2bf(float f) {
    uint32 u = __float_as_uint(f);
    u += 0x7fffu + ((u >> 16) & 1u);   // round-to-nearest-even
    return (ushort_t)(u >> 16);
}
__device__ __forceinline__ uint32 pk2(float lo, float hi) {
    return (uint32)f2bf(lo) | ((uint32)f2bf(hi) << 16);
}

// Pre-convert weights to bf16 and pre-gather rpe bias into [6][49][64] fp32.
__global__ void wmsa_prologue(const float* __restrict__ qkv_w,
                              const float* __restrict__ proj_w,
                              const float* __restrict__ rpe_table,
                              const int*   __restrict__ rpe_idx,
                              ushort_t* __restrict__ qkv_wb,
                              ushort_t* __restrict__ proj_wb,
                              float* __restrict__ biasws)
{
    int i = blockIdx.x * 256 + threadIdx.x;
    if (i < 110592) {
        qkv_wb[i] = f2bf(qkv_w[i]);
    } else if (i < 147456) {
        proj_wb[i - 110592] = f2bf(proj_w[i - 110592]);
    } else if (i < 147456 + NH * NTOK * 64) {
        int r = i - 147456;
        int h = r / (NTOK * 64);
        int rem = r - h * (NTOK * 64);
        int n = rem >> 6, m = rem & 63;
        biasws[r] = (m < NTOK) ? rpe_table[rpe_idx[n * NTOK + m] * NH + h] : 0.f;
    }
}

// Round-6 plan: round-4's N-split GEMM (4 MFMA per B-load, A re-read per ks
// from LDS) WITHOUT the 48-reg persistent out_acc. Completed heads 0..3 are
// packed to bf16 (16 VGPR) and flushed into xs after the pass-2 GEMM barrier
// (x dead there). Peak unified ~155 <= 170 -> 3 waves/SIMD = LDS's 3 blocks/CU.
// (r3: afr preload -> 188 unified, 2 waves. r5: M-split -> 1 MFMA/B-load, slow.)
__global__ __launch_bounds__(256, 3)
void wmsa_mfma(const float* __restrict__ x,
               const ushort_t* __restrict__ qkv_wb,
               const float* __restrict__ qkv_b,
               const ushort_t* __restrict__ proj_wb,
               const float* __restrict__ proj_b,
               const float* __restrict__ biasws,
               float* __restrict__ out)
{
    __shared__ alignas(16) ushort_t lds[LDS_TOT];
    ushort_t* const xs  = lds + OFF_XS;    // x (all 3 passes), then attn out
    ushort_t* const qks = lds + OFF_QKS;   // per-pass q|k (2 heads)
    ushort_t* const Pb  = lds + OFF_PB;    // probabilities, wave-local rows
    ushort_t* const Vt  = lds + OFF_VT;    // per-pass V^T (2 heads), zero-pad

    const int b    = blockIdx.x;
    const int t    = threadIdx.x;
    const int w    = t >> 6;      // wave 0..3
    const int lane = t & 63;
    const int quad = lane >> 4;   // MFMA k-group
    const int c    = lane & 15;   // MFMA row/col within group
    const float scale = 0.17677669529663687f;   // 32^-0.5
    const floatx4 zf = {0.f, 0.f, 0.f, 0.f};

    const float* xb = x + (size_t)b * (NTOK * CDIM);

    // ---------- stage x -> bf16 LDS (coalesced float4) ----------
    for (int i = t; i < (NTOK * CDIM) / 4; i += 256) {
        int e = i * 4;
        int n = e / CDIM, d = e - n * CDIM;
        float4 v = *(const float4*)(xb + e);
        ushort_t* p = &xs[n * XS_S + d];
        p[0] = f2bf(v.x); p[1] = f2bf(v.y); p[2] = f2bf(v.z); p[3] = f2bf(v.w);
    }
    __syncthreads();                                   // (A) x staged

    // packed PV outputs for heads 0..3 (bf16 pairs): 16 VGPR, static indices.
    uint32 out_pk[4][2][2];

    const int hh_w   = w >> 1;          // GEMM col-tile roles
    const int half_w = w & 1;
    const int jcol   = hh_w * 64 + half_w * 16 + c;   // q col in qks; k at +32
    const int vrow   = w * 16 + c;                    // V^T row (= d index)
    const int arow   = w * 16 + c;                    // attention query row

    #pragma unroll
    for (int pass = 0; pass < 3; ++pass) {
        // ----- qkv GEMM: wave owns (hh_w,half_w) col-tile of q,k,v; all 4 m-tiles
        const int jb = (2 * pass + hh_w) * HD + half_w * 16 + c;
        const ushort_t* wp0 = qkv_wb + jb * CDIM + quad * 8;

        floatx4 acc[3][4];
        #pragma unroll
        for (int s = 0; s < 3; ++s)
            #pragma unroll
            for (int mt = 0; mt < 4; ++mt) acc[s][mt] = zf;

        #pragma unroll
        for (int ks = 0; ks < 6; ++ks) {
            short8 a4[4];
            #pragma unroll
            for (int mt = 0; mt < 4; ++mt)   // rows>=49 garbage, masked below
                a4[mt] = *(const short8*)&xs[(mt * 16 + c) * XS_S + ks * 32 + quad * 8];
            #pragma unroll
            for (int s = 0; s < 3; ++s) {
                short8 bf = *(const short8*)(wp0 + s * (CDIM * CDIM) + ks * 32);
                #pragma unroll
                for (int mt = 0; mt < 4; ++mt)
                    acc[s][mt] = __builtin_amdgcn_mfma_f32_16x16x32_bf16(
                        a4[mt], bf, acc[s][mt], 0, 0, 0);
            }
        }
        // epilogue: q,k -> qks; v -> Vt transposed (row = d, col = token)
        float bq = qkv_b[jb];
        float bk = qkv_b[CDIM + jb];
        float bv = qkv_b[2 * CDIM + jb];
        #pragma unroll
        for (int mt = 0; mt < 4; ++mt) {
            #pragma unroll
            for (int r = 0; r < 4; ++r) {
                int n = mt * 16 + quad * 4 + r;   // C: col=lane&15, row=quad*4+reg
                if (n < NTOK) {
                    qks[n * QK_S + jcol]      = f2bf((acc[0][mt][r] + bq) * scale);
                    qks[n * QK_S + jcol + 32] = f2bf(acc[1][mt][r] + bk);
                }
                Vt[vrow * VT_S + n] = (n < NTOK) ? f2bf(acc[2][mt][r] + bv)
                                                 : (ushort_t)0;
            }
        }
        __syncthreads();   // (B_p) qks + Vt ready; pass 2: last x read retired

        // ----- pass 2 only: flush packed heads 0..3 into xs (x now dead) -----
        if (pass == 2) {
            #pragma unroll
            for (int h2 = 0; h2 < 4; ++h2)
                #pragma unroll
                for (int nt = 0; nt < 2; ++nt)
                    #pragma unroll
                    for (int r = 0; r < 4; ++r) {
                        int n = w * 16 + quad * 4 + r;
                        if (n < NTOK) {
                            uint32 d = out_pk[h2][nt][r >> 1];
                            xs[n * XS_S + h2 * HD + nt * 16 + c] =
                                (ushort_t)((r & 1) ? (d >> 16) : (d & 0xffffu));
                        }
                    }
        }

        // ----- attention, 2 heads, no intra-pass barriers (Pb wave-local) ----
        #pragma unroll
        for (int hh = 0; hh < 2; ++hh) {
            const int h = pass * 2 + hh;

            short8 aq = *(const short8*)&qks[arow * QK_S + hh * 64 + quad * 8];
            floatx4 sacc[4];
            #pragma unroll
            for (int nt = 0; nt < 4; ++nt) {
                short8 bk8 = *(const short8*)&qks[(nt * 16 + c) * QK_S + hh * 64 + 32 + quad * 8];
                sacc[nt] = __builtin_amdgcn_mfma_f32_16x16x32_bf16(aq, bk8, zf, 0, 0, 0);
            }

            const float* bpb = biasws + h * (NTOK * 64);
            #pragma unroll
            for (int r = 0; r < 4; ++r) {
                int n  = w * 16 + quad * 4 + r;
                int nc = (n < NTOK) ? n : (NTOK - 1);   // clamp for pad rows
                float sv[4];
                #pragma unroll
                for (int nt = 0; nt < 4; ++nt) {
                    int col = nt * 16 + c;
                    float bias = bpb[nc * 64 + col];
                    sv[nt] = (col < NTOK) ? (sacc[nt][r] + bias) : -1e30f;
                }
                float m0 = fmaxf(fmaxf(sv[0], sv[1]), fmaxf(sv[2], sv[3]));
                m0 = fmaxf(m0, __shfl_xor(m0, 1));
                m0 = fmaxf(m0, __shfl_xor(m0, 2));
                m0 = fmaxf(m0, __shfl_xor(m0, 4));
                m0 = fmaxf(m0, __shfl_xor(m0, 8));
                float ex[4], s0 = 0.f;
                #pragma unroll
                for (int nt = 0; nt < 4; ++nt) { ex[nt] = __expf(sv[nt] - m0); s0 += ex[nt]; }
                s0 += __shfl_xor(s0, 1);
                s0 += __shfl_xor(s0, 2);
                s0 += __shfl_xor(s0, 4);
                s0 += __shfl_xor(s0, 8);
                float inv = 1.f / s0;
                if (n < NTOK) {
                    #pragma unroll
                    for (int nt = 0; nt < 4; ++nt)   // cols 49..63 exact 0 (K-pad)
                        Pb[n * P_S + nt * 16 + c] = f2bf(ex[nt] * inv);
                }
            }

            // PV: [16x64(pad)] @ [64x32]
            floatx4 o2[2]; o2[0] = zf; o2[1] = zf;
            #pragma unroll
            for (int ks2 = 0; ks2 < 2; ++ks2) {
                short8 ap = *(const short8*)&Pb[arow * P_S + ks2 * 32 + quad * 8];
                #pragma unroll
                for (int nt = 0; nt < 2; ++nt) {
                    short8 bv8 = *(const short8*)&Vt[(hh * HD + nt * 16 + c) * VT_S + ks2 * 32 + quad * 8];
                    o2[nt] = __builtin_amdgcn_mfma_f32_16x16x32_bf16(ap, bv8, o2[nt], 0, 0, 0);
                }
            }
            if (pass < 2) {
                // pack to bf16 pairs (same rounding as the eventual xs write)
                #pragma unroll
                for (int nt = 0; nt < 2; ++nt) {
                    out_pk[h][nt][0] = pk2(o2[nt][0], o2[nt][1]);
                    out_pk[h][nt][1] = pk2(o2[nt][2], o2[nt][3]);
                }
            } else {
                #pragma unroll
                for (int nt = 0; nt < 2; ++nt)
                    #pragma unroll
                    for (int r = 0; r < 4; ++r) {
                        int n = w * 16 + quad * 4 + r;
                        if (n < NTOK)
                            xs[n * XS_S + h * HD + nt * 16 + c] = f2bf(o2[nt][r]);
                    }
            }
        }
        __syncthreads();   // (C_p) release qks/Vt; after pass 2: attn-out ready
    }

    // ---------- output projection: [49x192] @ [192x192]^T ----------
    floatx4 pacc[3][4];
    #pragma unroll
    for (int tt = 0; tt < 3; ++tt)
        #pragma unroll
        for (int mt = 0; mt < 4; ++mt) pacc[tt][mt] = zf;

    #pragma unroll
    for (int ks = 0; ks < 6; ++ks) {
        short8 a4[4];
        #pragma unroll
        for (int mt = 0; mt < 4; ++mt)
            a4[mt] = *(const short8*)&xs[(mt * 16 + c) * XS_S + ks * 32 + quad * 8];
        #pragma unroll
        for (int tt = 0; tt < 3; ++tt) {
            int j = (tt * 4 + w) * 16 + c;
            short8 bf = *(const short8*)&proj_wb[j * CDIM + ks * 32 + quad * 8];
            #pragma unroll
            for (int mt = 0; mt < 4; ++mt)
                pacc[tt][mt] = __builtin_amdgcn_mfma_f32_16x16x32_bf16(
                    a4[mt], bf, pacc[tt][mt], 0, 0, 0);
        }
    }
    #pragma unroll
    for (int tt = 0; tt < 3; ++tt) {
        int j = (tt * 4 + w) * 16 + c;
        float pb = proj_b[j];
        #pragma unroll
        for (int mt = 0; mt < 4; ++mt)
            #pragma unroll
            for (int r = 0; r < 4; ++r) {
                int n = mt * 16 + quad * 4 + r;
                if (n < NTOK)
                    out[((size_t)b * NTOK + n) * CDIM + j] = pacc[tt][mt][r] + pb;
            }
    }
}

extern "C" void kernel_launch(void* const* d_in, const int* in_sizes, int n_in,
                              void* d_out, int out_size, void* d_ws, size_t ws_size,
                              hipStream_t stream)
{
    const float* x      = (const float*)d_in[0];
    const float* qkv_w  = (const float*)d_in[1];
    const float* qkv_b  = (const float*)d_in[2];
    const float* proj_w = (const float*)d_in[3];
    const float* proj_b = (const float*)d_in[4];
    const float* rpe_t  = (const float*)d_in[5];
    const int*   rpe_i  = (const int*)d_in[6];
    float*       o      = (float*)d_out;

    // workspace layout: qkv_w bf16 (221184 B) | proj_w bf16 (73728 B) | bias fp32 (75264 B)
    ushort_t* qkv_wb  = (ushort_t*)d_ws;
    ushort_t* proj_wb = qkv_wb + 110592;
    float*    biasws  = (float*)((char*)d_ws + (110592 + 36864) * sizeof(ushort_t));

    int tot = 147456 + NH * NTOK * 64;
    wmsa_prologue<<<dim3((tot + 255) / 256), dim3(256), 0, stream>>>(
        qkv_w, proj_w, rpe_t, rpe_i, qkv_wb, proj_wb, biasws);
    wmsa_mfma<<<dim3(NWIN), dim3(256), 0, stream>>>(
        x, qkv_wb, qkv_b, proj_wb, proj_b, biasws, o);
}